// Round 14
// baseline (55.834 us; speedup 1.0000x reference)
//
#include <hip/hip_runtime.h>
#include <math.h>

// Shapes: x:(64,196,768) f32, ln_w/ln_b:(768,), sw/sb:(196,2,196), dw:(196,2)
//   W[o,n] = sum_m dw[o,m]*sw[o,m,n];  c[o] = sum_m dw[o,m]*sum_n sb[o,m,n]
//   t[b,o,d] = sum_n W[o,n]*(xh*ln_w)[b,n,d] + ln_b[d]*rowsum[o] + c[o]
//   out[b,o,d] = x[b,o,d] * (gelu_erf(t) + 1)
// bf16 split MFMA: acc += Whi*Bhi + Whi*Blo + Wlo*Bhi (lo*lo dropped).
// R14: R13 was latency-bound with VGPR=48 == exactly one chunk of loads ->
// compiler serialized chunks into ~5 HBM round-trips each. Fix: B staging via
// __builtin_amdgcn_global_load_lds (async DMA, no VGPR cost, whole chunk in
// flight); m97 2-barrier loop overlaps stage(c+1) with MFMA(c). A = 1-ahead
// VGPR prefetch from L2. Producer/prep unchanged from R13.

#define B_   64
#define N_   196
#define D_   768
#define KQ   7     // 7 chunks of 32 k
#define NKO  28    // 28 k-octets = 224 padded k
#define OPAD 256

typedef __attribute__((ext_vector_type(8))) short bf16x8;
typedef __attribute__((ext_vector_type(4))) float f32x4;

__device__ __forceinline__ unsigned short bf16_rne(float f) {
    unsigned u = __builtin_bit_cast(unsigned, f);
    u += 0x7FFFu + ((u >> 16) & 1u);
    return (unsigned short)(u >> 16);
}
__device__ __forceinline__ float bf16_to_f(unsigned short h) {
    unsigned u = ((unsigned)h) << 16;
    return __builtin_bit_cast(float, u);
}

typedef __attribute__((address_space(3))) unsigned int lds_u32_t;
typedef const __attribute__((address_space(1))) unsigned int glb_u32_t;
__device__ __forceinline__ void gload_lds16(const void* g, void* l) {
    __builtin_amdgcn_global_load_lds((glb_u32_t*)g, (lds_u32_t*)l, 16, 0, 0);
}

// Wfh/Wfl frag-packed: addr = (((o>>4)*KQ + (k>>5))*4 + ((k>>3)&3))*128
//                             + (o&15)*8 + (k&7);  o>=196 / k>=224 zeroed.
__global__ void prep_w_kernel(const float* __restrict__ sw,
                              const float* __restrict__ sb,
                              const float* __restrict__ dw,
                              unsigned short* __restrict__ Wfh,
                              unsigned short* __restrict__ Wfl,
                              float* __restrict__ rowsum,
                              float* __restrict__ cvec) {
    int o = blockIdx.x;   // 0..255
    int t = threadIdx.x;  // k; only t<224 stored
    float w0 = 0.f, w1 = 0.f;
    if (o < N_) { w0 = dw[o * 2 + 0]; w1 = dw[o * 2 + 1]; }
    float val = 0.f, sbp = 0.f;
    if (o < N_ && t < N_) {
        val = w0 * sw[(o * 2 + 0) * N_ + t] + w1 * sw[(o * 2 + 1) * N_ + t];
        sbp = w0 * sb[(o * 2 + 0) * N_ + t] + w1 * sb[(o * 2 + 1) * N_ + t];
    }
    if (t < KQ * 32) {
        unsigned short h = bf16_rne(val);
        int addr = (((o >> 4) * KQ + (t >> 5)) * 4 + ((t >> 3) & 3)) * 128
                 + (o & 15) * 8 + (t & 7);
        Wfh[addr] = h;
        Wfl[addr] = bf16_rne(val - bf16_to_f(h));
    }
    __shared__ float r1[256], r2[256];
    r1[t] = val; r2[t] = sbp;
    __syncthreads();
    for (int s = 128; s > 0; s >>= 1) {
        if (t < s) { r1[t] += r1[t + s]; r2[t] += r2[t + s]; }
        __syncthreads();
    }
    if (t == 0) { rowsum[o] = r1[0]; cvec[o] = r2[0]; }
}

// Producer: block (koct, b), 512 thr = 8 waves; wave w owns row k=koct*8+w.
// One-pass stats, normalize*ln_w to LDS f32 [8][768], transpose to Bh/Bl
// packed [b][koct][d][k8] (hi/lo bf16), 16B/thread contiguous stores.
// k>=196 rows are zeros (v=0 -> xs=0).
__global__ __launch_bounds__(512) void ln_split_kernel(
    const float* __restrict__ x,
    const float* __restrict__ ln_w,
    unsigned short* __restrict__ Bh,
    unsigned short* __restrict__ Bl) {
    const int koct = blockIdx.x, b = blockIdx.y;
    const int t = threadIdx.x, w = t >> 6, lane = t & 63;
    const int k = koct * 8 + w;
    __shared__ float xs[8][768];

    float4 v0 = make_float4(0.f, 0.f, 0.f, 0.f);
    float4 v1 = v0, v2 = v0;
    if (k < N_) {
        const float4* xr = reinterpret_cast<const float4*>(x + ((size_t)b * N_ + k) * D_);
        v0 = xr[lane]; v1 = xr[lane + 64]; v2 = xr[lane + 128];
    }
    float s = v0.x + v0.y + v0.z + v0.w
            + v1.x + v1.y + v1.z + v1.w
            + v2.x + v2.y + v2.z + v2.w;
    float q = v0.x*v0.x + v0.y*v0.y + v0.z*v0.z + v0.w*v0.w
            + v1.x*v1.x + v1.y*v1.y + v1.z*v1.z + v1.w*v1.w
            + v2.x*v2.x + v2.y*v2.y + v2.z*v2.z + v2.w*v2.w;
    #pragma unroll
    for (int off = 32; off >= 1; off >>= 1) {
        s += __shfl_xor(s, off);
        q += __shfl_xor(q, off);
    }
    const float mu   = s * (1.0f / D_);
    const float var  = q * (1.0f / D_) - mu * mu;
    const float rstd = rsqrtf(var + 1e-5f);

    const float4* lw4 = reinterpret_cast<const float4*>(ln_w);
    float4 w0 = lw4[lane], w1 = lw4[lane + 64], w2 = lw4[lane + 128];
    float4 o0, o1, o2;
    o0.x = (v0.x - mu) * rstd * w0.x;  o0.y = (v0.y - mu) * rstd * w0.y;
    o0.z = (v0.z - mu) * rstd * w0.z;  o0.w = (v0.w - mu) * rstd * w0.w;
    o1.x = (v1.x - mu) * rstd * w1.x;  o1.y = (v1.y - mu) * rstd * w1.y;
    o1.z = (v1.z - mu) * rstd * w1.z;  o1.w = (v1.w - mu) * rstd * w1.w;
    o2.x = (v2.x - mu) * rstd * w2.x;  o2.y = (v2.y - mu) * rstd * w2.y;
    o2.z = (v2.z - mu) * rstd * w2.z;  o2.w = (v2.w - mu) * rstd * w2.w;
    *reinterpret_cast<float4*>(&xs[w][lane * 4])       = o0;
    *reinterpret_cast<float4*>(&xs[w][lane * 4 + 256]) = o1;
    *reinterpret_cast<float4*>(&xs[w][lane * 4 + 512]) = o2;
    __syncthreads();

    for (int d = t; d < D_; d += 512) {
        bf16x8 hv, lv;
        #pragma unroll
        for (int kk = 0; kk < 8; ++kk) {
            float v = xs[kk][d];
            unsigned short h = bf16_rne(v);
            hv[kk] = (short)h;
            lv[kk] = (short)bf16_rne(v - bf16_to_f(h));
        }
        const size_t base = (((size_t)b * NKO + koct) * D_ + d) * 8;
        *reinterpret_cast<bf16x8*>(Bh + base) = hv;
        *reinterpret_cast<bf16x8*>(Bl + base) = lv;
    }
}

// Consumer GEMM: grid (12 dt, 64 b), 512 thr = 8 waves.
// B staged via global_load_lds (async DMA): per chunk, threads 0..255 stage
// BsH (cell = (w&3)*64+lane, 16B each), threads 256..511 stage BsL. m97
// 2-barrier loop: stage(c+1) in flight during MFMA(c); one syncthreads/chunk.
// A = 1-ahead VGPR prefetch from L2 (frag-packed Wfh/Wfl).
__global__ __launch_bounds__(512, 4) void gemm_bpk_kernel(
    const float* __restrict__ x,
    const float* __restrict__ ln_b,
    const unsigned short* __restrict__ Wfh,
    const unsigned short* __restrict__ Wfl,
    const unsigned short* __restrict__ Bh,
    const unsigned short* __restrict__ Bl,
    const float* __restrict__ rowsum,
    const float* __restrict__ cvec,
    float* __restrict__ out) {
    const int b  = blockIdx.y;
    const int d0 = blockIdx.x * 64;
    const int t = threadIdx.x;
    const int w = t >> 6, lane = t & 63;
    const int m16 = lane & 15, g = lane >> 4;

    __shared__ __align__(16) unsigned short BsH[2][2048];  // [buf][koct4][d64][k8]
    __shared__ __align__(16) unsigned short BsL[2][2048];

    const float* xb = x + (size_t)b * (N_ * D_);

    // staging roles: half = 0 -> BsH, half = 1 -> BsL; cell 0..255
    const int half = w >> 2;
    const int cell = (w & 3) * 64 + lane;
    const int skoct = cell >> 6, sd = cell & 63;
    const unsigned short* sbase = (half ? Bl : Bh)
        + (((size_t)b * NKO + skoct) * D_ + d0 + sd) * 8;

    f32x4 acc[2][4];
    #pragma unroll
    for (int i = 0; i < 2; ++i)
        #pragma unroll
        for (int j = 0; j < 4; ++j)
            acc[i][j] = (f32x4){0.f, 0.f, 0.f, 0.f};

    bf16x8 ah[2][2], al[2][2];
    #pragma unroll
    for (int mf = 0; mf < 2; ++mf) {
        const size_t ab = ((size_t)((w * 2 + mf) * KQ)) * 512 + lane * 8;
        ah[0][mf] = *reinterpret_cast<const bf16x8*>(Wfh + ab);
        al[0][mf] = *reinterpret_cast<const bf16x8*>(Wfl + ab);
    }

    // prologue: stage chunk 0 (async) then barrier (drains vmcnt)
    gload_lds16(sbase, (half ? &BsL[0][cell * 8] : &BsH[0][cell * 8]));
    __syncthreads();

    #pragma unroll
    for (int c = 0; c < KQ; ++c) {
        const int s = c & 1;
        if (c + 1 < KQ) {
            // async stage of next chunk into other buffer (in flight during MFMA)
            gload_lds16(sbase + (size_t)(c + 1) * 4 * D_ * 8,
                        (half ? &BsL[s ^ 1][cell * 8] : &BsH[s ^ 1][cell * 8]));
            // A prefetch for next chunk (L2-resident)
            #pragma unroll
            for (int mf = 0; mf < 2; ++mf) {
                const size_t ab = ((size_t)((w * 2 + mf) * KQ + c + 1)) * 512 + lane * 8;
                ah[s ^ 1][mf] = *reinterpret_cast<const bf16x8*>(Wfh + ab);
                al[s ^ 1][mf] = *reinterpret_cast<const bf16x8*>(Wfl + ab);
            }
        }
        #pragma unroll
        for (int nf = 0; nf < 4; ++nf) {
            const int ba = (g * 64 + nf * 16 + m16) * 8;
            bf16x8 bh = *reinterpret_cast<const bf16x8*>(&BsH[s][ba]);
            bf16x8 bl = *reinterpret_cast<const bf16x8*>(&BsL[s][ba]);
            #pragma unroll
            for (int mf = 0; mf < 2; ++mf) {
                acc[mf][nf] = __builtin_amdgcn_mfma_f32_16x16x32_bf16(ah[s][mf], bh, acc[mf][nf], 0, 0, 0);
                acc[mf][nf] = __builtin_amdgcn_mfma_f32_16x16x32_bf16(ah[s][mf], bl, acc[mf][nf], 0, 0, 0);
                acc[mf][nf] = __builtin_amdgcn_mfma_f32_16x16x32_bf16(al[s][mf], bh, acc[mf][nf], 0, 0, 0);
            }
        }
        __syncthreads();  // waves done reading buf s; stage(c+1) drained
    }

    // epilogue: T = acc + lnb[d]*rowsum[o] + c[o]; out = x*(gelu(T)+1)
    // C/D layout: col(d) = lane&15, row(o within frag) = g*4 + r
    float lbv[4];
    #pragma unroll
    for (int nf = 0; nf < 4; ++nf) lbv[nf] = ln_b[d0 + nf * 16 + m16];
    #pragma unroll
    for (int mf = 0; mf < 2; ++mf) {
        const int obase = (w * 2 + mf) * 16 + g * 4;
        f32x4 rs4 = *reinterpret_cast<const f32x4*>(rowsum + obase);
        f32x4 cc4 = *reinterpret_cast<const f32x4*>(cvec + obase);
        float xres[4][4];
        #pragma unroll
        for (int r = 0; r < 4; ++r) {
            const int o = obase + r;
            #pragma unroll
            for (int nf = 0; nf < 4; ++nf)
                xres[r][nf] = (o < N_) ? xb[(size_t)o * D_ + d0 + nf * 16 + m16] : 0.f;
        }
        #pragma unroll
        for (int r = 0; r < 4; ++r) {
            const int o = obase + r;
            if (o < N_) {
                #pragma unroll
                for (int nf = 0; nf < 4; ++nf) {
                    const int d = d0 + nf * 16 + m16;
                    float T = acc[mf][nf][r] + fmaf(lbv[nf], rs4[r], cc4[r]);
                    float gl = 0.5f * T * (1.0f + erff(T * 0.70710678118654752f));
                    out[((size_t)(b * N_ + o)) * D_ + d] = xres[r][nf] * (gl + 1.0f);
                }
            }
        }
    }
}

// ---------------- FALLBACK PATH (R10, proven) ----------------
__global__ void ln_stats_kernel(const float* __restrict__ x,
                                float* __restrict__ mu,
                                float* __restrict__ rstd) {
    int wave = threadIdx.x >> 6;
    int lane = threadIdx.x & 63;
    int row  = blockIdx.x * 4 + wave;
    const float4* xr = reinterpret_cast<const float4*>(x + (size_t)row * D_);
    float4 v0 = xr[lane];
    float4 v1 = xr[lane + 64];
    float4 v2 = xr[lane + 128];
    float s = v0.x + v0.y + v0.z + v0.w
            + v1.x + v1.y + v1.z + v1.w
            + v2.x + v2.y + v2.z + v2.w;
    #pragma unroll
    for (int off = 32; off >= 1; off >>= 1) s += __shfl_xor(s, off);
    float m = s * (1.0f / D_);
    float q = 0.f;
    {
        float d;
        d = v0.x - m; q += d * d;  d = v0.y - m; q += d * d;
        d = v0.z - m; q += d * d;  d = v0.w - m; q += d * d;
        d = v1.x - m; q += d * d;  d = v1.y - m; q += d * d;
        d = v1.z - m; q += d * d;  d = v1.w - m; q += d * d;
        d = v2.x - m; q += d * d;  d = v2.y - m; q += d * d;
        d = v2.z - m; q += d * d;  d = v2.w - m; q += d * d;
    }
    #pragma unroll
    for (int off = 32; off >= 1; off >>= 1) q += __shfl_xor(q, off);
    if (lane == 0) {
        mu[row]   = m;
        rstd[row] = rsqrtf(q * (1.0f / D_) + 1e-5f);
    }
}

#define LOADC(s, c) do {                                                      \
    _Pragma("unroll")                                                         \
    for (int e = 0; e < 4; ++e) {                                             \
        const int k = (c) * 32 + w * 4 + e;                                   \
        if (k < N_) {                                                         \
            xv[s][e]  = xb[(size_t)k * D_ + d0 + lane];                       \
            mus[s][e] = mub[k];                                               \
            rss[s][e] = rsb[k];                                               \
        } else { xv[s][e] = 0.f; mus[s][e] = 0.f; rss[s][e] = 0.f; }          \
    } } while (0)

#define WRITEC(s) do {                                                        \
    short4 hv, lv; short* hp = &hv.x; short* lp = &lv.x;                      \
    _Pragma("unroll")                                                         \
    for (int e = 0; e < 4; ++e) {                                             \
        float v = (xv[s][e] - mus[s][e]) * rss[s][e];                         \
        unsigned short h = bf16_rne(v);                                       \
        hp[e] = (short)h;                                                     \
        lp[e] = (short)bf16_rne(v - bf16_to_f(h));                            \
    }                                                                         \
    const int ea = ((w >> 1) * 64 + lane) * 8 + (w & 1) * 4;                  \
    *reinterpret_cast<short4*>(&FbH[s][ea]) = hv;                             \
    *reinterpret_cast<short4*>(&FbL[s][ea]) = lv; } while (0)

#define LOADA(slot, c) do {                                                   \
    _Pragma("unroll")                                                         \
    for (int mf = 0; mf < 2; ++mf) {                                          \
        const size_t ab = ((size_t)((w * 2 + mf) * KQ + (c)) * 512) + lane * 8;\
        ah[slot][mf] = *reinterpret_cast<const bf16x8*>(Wfh + ab);            \
        al[slot][mf] = *reinterpret_cast<const bf16x8*>(Wfl + ab);            \
    } } while (0)

__global__ __launch_bounds__(512, 4) void gemm_lds_kernel(
    const float* __restrict__ x,
    const float* __restrict__ ln_w,
    const float* __restrict__ ln_b,
    const unsigned short* __restrict__ Wfh,
    const unsigned short* __restrict__ Wfl,
    const float* __restrict__ rowsum,
    const float* __restrict__ cvec,
    const float* __restrict__ mu,
    const float* __restrict__ rstd,
    float* __restrict__ out) {
    const int b  = blockIdx.y;
    const int d0 = blockIdx.x * 64;
    const int t = threadIdx.x;
    const int w = t >> 6, lane = t & 63;
    const int m16 = lane & 15, g = lane >> 4;

    __shared__ __align__(16) unsigned short FbH[2][2048];
    __shared__ __align__(16) unsigned short FbL[2][2048];

    const float* xb  = x + (size_t)b * (N_ * D_);
    const float* mub = mu + b * N_;
    const float* rsb = rstd + b * N_;

    float xv[2][4], mus[2][4], rss[2][4];
    bf16x8 ah[2][2], al[2][2];

    f32x4 acc[2][4];
    #pragma unroll
    for (int i = 0; i < 2; ++i)
        #pragma unroll
        for (int j = 0; j < 4; ++j)
            acc[i][j] = (f32x4){0.f, 0.f, 0.f, 0.f};

    LOADC(0, 0);
    LOADC(1, 1);
    LOADA(0, 0);
    WRITEC(0);
    __syncthreads();

    #pragma unroll
    for (int c = 0; c < KQ; ++c) {
        const int s = c & 1;
        if (c > 0) {
            WRITEC(s);
            __syncthreads();
        }
        if (c + 2 < KQ) LOADC(s, c + 2);
        if (c + 1 < KQ) LOADA((c + 1) & 1, c + 1);
        #pragma unroll
        for (int nf = 0; nf < 4; ++nf) {
            const int ba = (g * 64 + nf * 16 + m16) * 8;
            bf16x8 bh = *reinterpret_cast<const bf16x8*>(&FbH[s][ba]);
            bf16x8 bl = *reinterpret_cast<const bf16x8*>(&FbL[s][ba]);
            #pragma unroll
            for (int mf = 0; mf < 2; ++mf) {
                acc[mf][nf] = __builtin_amdgcn_mfma_f32_16x16x32_bf16(ah[s][mf], bh, acc[mf][nf], 0, 0, 0);
                acc[mf][nf] = __builtin_amdgcn_mfma_f32_16x16x32_bf16(ah[s][mf], bl, acc[mf][nf], 0, 0, 0);
                acc[mf][nf] = __builtin_amdgcn_mfma_f32_16x16x32_bf16(al[s][mf], bh, acc[mf][nf], 0, 0, 0);
            }
        }
    }

    float lwv[4], lbv[4];
    #pragma unroll
    for (int nf = 0; nf < 4; ++nf) {
        lwv[nf] = ln_w[d0 + nf * 16 + m16];
        lbv[nf] = ln_b[d0 + nf * 16 + m16];
    }
    #pragma unroll
    for (int mf = 0; mf < 2; ++mf) {
        #pragma unroll
        for (int r = 0; r < 4; ++r) {
            const int o = w * 32 + mf * 16 + g * 4 + r;
            if (o < N_) {
                const float rs = rowsum[o], cc = cvec[o];
                #pragma unroll
                for (int nf = 0; nf < 4; ++nf) {
                    const int d = d0 + nf * 16 + m16;
                    float T = fmaf(lwv[nf], acc[mf][nf][r], fmaf(lbv[nf], rs, cc));
                    float gl = 0.5f * T * (1.0f + erff(T * 0.70710678118654752f));
                    out[((size_t)(b * N_ + o)) * D_ + d] = xb[(size_t)o * D_ + d] * (gl + 1.0f);
                }
            }
        }
    }
}

extern "C" void kernel_launch(void* const* d_in, const int* in_sizes, int n_in,
                              void* d_out, int out_size, void* d_ws, size_t ws_size,
                              hipStream_t stream) {
    const float* x    = (const float*)d_in[0];
    const float* ln_w = (const float*)d_in[1];
    const float* ln_b = (const float*)d_in[2];
    const float* sw   = (const float*)d_in[3];
    const float* sb   = (const float*)d_in[4];
    const float* dw   = (const float*)d_in[5];
    float* out = (float*)d_out;

    float* wsf = (float*)d_ws;
    float* rowsum = wsf;                               // 256 f32
    float* cvec   = rowsum + OPAD;                     // 256 f32
    unsigned short* Wfh = (unsigned short*)(cvec + OPAD);   // 256*224 u16
    unsigned short* Wfl = Wfh + OPAD * (KQ * 32);           // 256*224 u16
    char* after = (char*)(Wfl + OPAD * (KQ * 32));

    const size_t bpk_elems = (size_t)B_ * NKO * D_ * 8;     // 11,010,048
    const size_t need = (size_t)(after - (char*)d_ws) + 2 * bpk_elems * sizeof(unsigned short);

    prep_w_kernel<<<OPAD, 256, 0, stream>>>(sw, sb, dw, Wfh, Wfl, rowsum, cvec);

    if (ws_size >= need) {
        unsigned short* Bh = (unsigned short*)after;
        unsigned short* Bl = Bh + bpk_elems;
        ln_split_kernel<<<dim3(NKO, B_), 512, 0, stream>>>(x, ln_w, Bh, Bl);
        gemm_bpk_kernel<<<dim3(12, B_), 512, 0, stream>>>(
            x, ln_b, Wfh, Wfl, Bh, Bl, rowsum, cvec, out);
    } else {
        float* mu   = (float*)after;
        float* rstd = mu + 12608;
        ln_stats_kernel<<<(B_ * N_) / 4, 256, 0, stream>>>(x, mu, rstd);
        gemm_lds_kernel<<<dim3(12, B_), 512, 0, stream>>>(
            x, ln_w, ln_b, Wfh, Wfl, rowsum, cvec, mu, rstd, out);
    }
}